// Round 1
// baseline (2341.552 us; speedup 1.0000x reference)
//
#include <hip/hip_runtime.h>
#include <hip/hip_bf16.h>

#define DEVFN __device__ __forceinline__

using bf16 = __hip_bfloat16;

constexpr int BB = 4, NP = 256, NM = 128, CC = 128, HH = 128;
constexpr float EPS = 1e-5f;

DEVFN float b2f(bf16 v){ return __bfloat162float(v); }
DEVFN bf16  f2b(float v){ return __float2bfloat16(v); }
DEVFN float sigm(float x){ return 1.0f / (1.0f + __expf(-x)); }

// ---------------- shared-memory layout for the LN+GEMM kernels ----------------
struct SmemT {
  float xs[64][132];        // 64 rows x 128 (pad to 132 -> 16B-aligned rows, bank-safe)
  float wlds[2][32][128];   // staged weight chunk(s), 32 k-rows x 128 cols
  float lgb[2][128];        // ln gamma/beta
  float ps[4][64], pss[4][64];
  float mu_s[64], rs_s[64];
  float msk[64];
};

// Stage 64 rows of x into LDS, LayerNorm them in place.
DEVFN void stage_ln(SmemT& sm, int t, long row0,
                    const float* __restrict__ x,
                    const float* __restrict__ lng, const float* __restrict__ lnb,
                    const float* __restrict__ mask)
{
  if (t < 128){ sm.lgb[0][t] = lng[t]; sm.lgb[1][t] = lnb[t]; }
  if (t >= 128 && t < 192){
    int r = t - 128;
    sm.msk[r] = mask ? mask[row0 + r] : 1.0f;
  }
  const float4* xg4 = reinterpret_cast<const float4*>(x + row0 * 128);
  #pragma unroll
  for (int q = 0; q < 8; ++q){
    float4 v = xg4[t + q * 256];
    int flat = (t + q * 256) * 4;
    int r = flat >> 7, c0 = flat & 127;
    *reinterpret_cast<float4*>(&sm.xs[r][c0]) = v;
  }
  __syncthreads();
  { // partial sums: 4 threads per row
    int r = t & 63, q = t >> 6;
    float s = 0.f, ss = 0.f;
    #pragma unroll
    for (int k = 0; k < 32; ++k){ float v = sm.xs[r][q*32 + k]; s += v; ss += v*v; }
    sm.ps[q][r] = s; sm.pss[q][r] = ss;
  }
  __syncthreads();
  if (t < 64){
    float s  = sm.ps[0][t] + sm.ps[1][t] + sm.ps[2][t] + sm.ps[3][t];
    float ss = sm.pss[0][t] + sm.pss[1][t] + sm.pss[2][t] + sm.pss[3][t];
    float mu = s * (1.0f/128.0f);
    float var = ss * (1.0f/128.0f) - mu*mu;
    sm.mu_s[t] = mu;
    sm.rs_s[t] = rsqrtf(var + EPS);
  }
  __syncthreads();
  {
    int r = t & 63, q = t >> 6;
    float mu = sm.mu_s[r], rs = sm.rs_s[r];
    #pragma unroll
    for (int k = 0; k < 32; ++k){
      int c = q*32 + k;
      sm.xs[r][c] = (sm.xs[r][c] - mu) * rs * sm.lgb[0][c] + sm.lgb[1][c];
    }
  }
  __syncthreads();
}

// One GEMM pass over the 64 LN'd rows in LDS.
// OUTMODE 0: out = sigmoid(x@wg+bg) * (x@wl+bl) * mask      -> bf16
// OUTMODE 1: out = sigmoid(x@wg+bg)                          -> bf16
// OUTMODE 2: out = eg * (x@wg+bg) * mask                     -> f32
template<int OUTMODE>
DEVFN void gemm_pass(SmemT& sm, int t, long row0,
                     const float* __restrict__ wg, const float* __restrict__ bg,
                     const float* __restrict__ wl, const float* __restrict__ bl,
                     const bf16* __restrict__ eg, void* __restrict__ outp)
{
  const int ri = t >> 4, hi = t & 15;   // 16 row-groups x 16 col-groups
  float accg[4][8];
  float accl[4][8];
  #pragma unroll
  for (int a = 0; a < 4; ++a)
    #pragma unroll
    for (int b = 0; b < 8; ++b){ accg[a][b] = 0.f; if (OUTMODE == 0) accl[a][b] = 0.f; }

  for (int kc = 0; kc < 4; ++kc){
    __syncthreads();   // protect wlds from previous chunk's readers
    {
      const float4* w4 = reinterpret_cast<const float4*>(wg + kc*32*128);
      #pragma unroll
      for (int q = 0; q < 4; ++q){
        float4 v = w4[t + q*256];
        int flat = (t + q*256) * 4;
        int kk = flat >> 7, c0 = flat & 127;
        *reinterpret_cast<float4*>(&sm.wlds[0][kk][c0]) = v;
      }
      if (OUTMODE == 0){
        const float4* w4b = reinterpret_cast<const float4*>(wl + kc*32*128);
        #pragma unroll
        for (int q = 0; q < 4; ++q){
          float4 v = w4b[t + q*256];
          int flat = (t + q*256) * 4;
          int kk = flat >> 7, c0 = flat & 127;
          *reinterpret_cast<float4*>(&sm.wlds[1][kk][c0]) = v;
        }
      }
    }
    __syncthreads();
    #pragma unroll
    for (int kk = 0; kk < 32; ++kk){
      const int k = kc*32 + kk;
      float xv[4];
      #pragma unroll
      for (int rr = 0; rr < 4; ++rr) xv[rr] = sm.xs[ri*4 + rr][k];
      float4 g0 = *reinterpret_cast<const float4*>(&sm.wlds[0][kk][hi*8]);
      float4 g1 = *reinterpret_cast<const float4*>(&sm.wlds[0][kk][hi*8 + 4]);
      float wgv[8] = {g0.x,g0.y,g0.z,g0.w,g1.x,g1.y,g1.z,g1.w};
      float wlv[8];
      if (OUTMODE == 0){
        float4 l0 = *reinterpret_cast<const float4*>(&sm.wlds[1][kk][hi*8]);
        float4 l1 = *reinterpret_cast<const float4*>(&sm.wlds[1][kk][hi*8 + 4]);
        wlv[0]=l0.x; wlv[1]=l0.y; wlv[2]=l0.z; wlv[3]=l0.w;
        wlv[4]=l1.x; wlv[5]=l1.y; wlv[6]=l1.z; wlv[7]=l1.w;
      }
      #pragma unroll
      for (int rr = 0; rr < 4; ++rr){
        #pragma unroll
        for (int hh = 0; hh < 8; ++hh){
          accg[rr][hh] = fmaf(xv[rr], wgv[hh], accg[rr][hh]);
          if (OUTMODE == 0) accl[rr][hh] = fmaf(xv[rr], wlv[hh], accl[rr][hh]);
        }
      }
    }
  }
  __syncthreads();   // wlds free for next pass

  #pragma unroll
  for (int rr = 0; rr < 4; ++rr){
    int r = ri*4 + rr;
    long grow = row0 + r;
    float m = sm.msk[r];
    #pragma unroll
    for (int hh = 0; hh < 8; ++hh){
      int h = hi*8 + hh;
      float a = accg[rr][hh] + bg[h];
      if (OUTMODE == 0){
        float val = sigm(a) * (accl[rr][hh] + bl[h]) * m;
        reinterpret_cast<bf16*>(outp)[grow*128 + h] = f2b(val);
      } else if (OUTMODE == 1){
        reinterpret_cast<bf16*>(outp)[grow*128 + h] = f2b(sigm(a));
      } else {
        float e = b2f(eg[grow*128 + h]);
        reinterpret_cast<float*>(outp)[grow*128 + h] = e * a * m;
      }
    }
  }
}

// MODE 0: single gated pair (for pocket_pair / mol_pair).  MODE 1: z-mode (two pairs + eg, masked).
template<int MODE>
__global__ __launch_bounds__(256)
void ln_gate_kernel(const float* __restrict__ x, const float* __restrict__ mask,
                    const float* __restrict__ lng, const float* __restrict__ lnb,
                    const float* __restrict__ wg1, const float* __restrict__ bg1,
                    const float* __restrict__ wl1, const float* __restrict__ bl1,
                    bf16* __restrict__ out1,
                    const float* __restrict__ wg2, const float* __restrict__ bg2,
                    const float* __restrict__ wl2, const float* __restrict__ bl2,
                    bf16* __restrict__ out2,
                    const float* __restrict__ we, const float* __restrict__ be,
                    bf16* __restrict__ oute)
{
  __shared__ SmemT sm;
  const int t = threadIdx.x;
  const long row0 = (long)blockIdx.x * 64;
  stage_ln(sm, t, row0, x, lng, lnb, (MODE == 1) ? mask : nullptr);
  gemm_pass<0>(sm, t, row0, wg1, bg1, wl1, bl1, nullptr, out1);
  if (MODE == 1){
    gemm_pass<0>(sm, t, row0, wg2, bg2, wl2, bl2, nullptr, out2);
    gemm_pass<1>(sm, t, row0, we, be, nullptr, nullptr, nullptr, oute);
  }
}

// Per-channel batched einsums: bsum[b,i,j,c] = sum_k ppg[b,i,k,c]*ab1[b,k,j,c]
//                                            + sum_k ab2[b,i,k,c]*mpg[b,j,k,c]
__global__ __launch_bounds__(256)
void einsum_kernel(const bf16* __restrict__ ppg, const bf16* __restrict__ ab1,
                   const bf16* __restrict__ ab2, const bf16* __restrict__ mpg,
                   float* __restrict__ bsum)
{
  const int t = threadIdx.x;
  const int c = t & 127, jh = t >> 7;
  const int b = blockIdx.y;
  const int it = blockIdx.x >> 3, jt = blockIdx.x & 7;
  const int i0 = it * 8;
  const int j0 = jt * 16 + jh * 8;

  float acc[8][8];
  #pragma unroll
  for (int i = 0; i < 8; ++i)
    #pragma unroll
    for (int j = 0; j < 8; ++j) acc[i][j] = 0.f;

  // block1: k over NP
  {
    const bf16* pa = ppg + ((long)(b*NP + i0) * NP) * HH + c;   // + ii*NP*HH + k*HH
    const bf16* pb = ab1 + ((long)b * NP) * NM * HH + (long)j0 * HH + c; // + k*NM*HH + jj*HH
    for (int k = 0; k < NP; ++k){
      float av[8], bv[8];
      #pragma unroll
      for (int ii = 0; ii < 8; ++ii) av[ii] = b2f(pa[ii*(NP*HH) + k*HH]);
      #pragma unroll
      for (int jj = 0; jj < 8; ++jj) bv[jj] = b2f(pb[k*(NM*HH) + jj*HH]);
      #pragma unroll
      for (int ii = 0; ii < 8; ++ii)
        #pragma unroll
        for (int jj = 0; jj < 8; ++jj)
          acc[ii][jj] = fmaf(av[ii], bv[jj], acc[ii][jj]);
    }
  }
  // block2: k over NM
  {
    const bf16* pa = ab2 + ((long)(b*NP + i0) * NM) * HH + c;   // + ii*NM*HH + k*HH
    const bf16* pb = mpg + ((long)(b*NM + j0) * NM) * HH + c;   // + jj*NM*HH + k*HH
    for (int k = 0; k < NM; ++k){
      float av[8], bv[8];
      #pragma unroll
      for (int ii = 0; ii < 8; ++ii) av[ii] = b2f(pa[ii*(NM*HH) + k*HH]);
      #pragma unroll
      for (int jj = 0; jj < 8; ++jj) bv[jj] = b2f(pb[jj*(NM*HH) + k*HH]);
      #pragma unroll
      for (int ii = 0; ii < 8; ++ii)
        #pragma unroll
        for (int jj = 0; jj < 8; ++jj)
          acc[ii][jj] = fmaf(av[ii], bv[jj], acc[ii][jj]);
    }
  }
  // store
  float* po = bsum + ((long)(b*NP + i0) * NM + j0) * CC + c;
  #pragma unroll
  for (int ii = 0; ii < 8; ++ii)
    #pragma unroll
    for (int jj = 0; jj < 8; ++jj)
      po[ii*(NM*CC) + jj*CC] = acc[ii][jj];
}

// Final: h = LN(bsum); out = eg * (h @ asw + asb) * mask
__global__ __launch_bounds__(256)
void final_kernel(const float* __restrict__ bsum, const bf16* __restrict__ eg,
                  const float* __restrict__ mask,
                  const float* __restrict__ lnhg, const float* __restrict__ lnhb,
                  const float* __restrict__ asw, const float* __restrict__ asb,
                  float* __restrict__ out)
{
  __shared__ SmemT sm;
  const int t = threadIdx.x;
  const long row0 = (long)blockIdx.x * 64;
  stage_ln(sm, t, row0, bsum, lnhg, lnhb, mask);
  gemm_pass<2>(sm, t, row0, asw, asb, nullptr, nullptr, eg, out);
}

extern "C" void kernel_launch(void* const* d_in, const int* in_sizes, int n_in,
                              void* d_out, int out_size, void* d_ws, size_t ws_size,
                              hipStream_t stream)
{
  const float* z     = (const float*)d_in[0];
  const float* zmask = (const float*)d_in[1];
  const float* pp    = (const float*)d_in[2];
  const float* mp    = (const float*)d_in[3];
  const float* ln_g  = (const float*)d_in[4];
  const float* ln_b  = (const float*)d_in[5];
  const float* lnh_g = (const float*)d_in[6];
  const float* lnh_b = (const float*)d_in[7];
  const float* gw1   = (const float*)d_in[8];
  const float* gb1   = (const float*)d_in[9];
  const float* gw2   = (const float*)d_in[10];
  const float* gb2   = (const float*)d_in[11];
  const float* w1    = (const float*)d_in[12];
  const float* b1    = (const float*)d_in[13];
  const float* w2    = (const float*)d_in[14];
  const float* b2    = (const float*)d_in[15];
  const float* egw   = (const float*)d_in[16];
  const float* egb   = (const float*)d_in[17];
  const float* asw   = (const float*)d_in[18];
  const float* asb   = (const float*)d_in[19];
  float* out = (float*)d_out;

  // workspace layout (bytes)
  const size_t ZE = (size_t)BB*NP*NM*HH;       // 16,777,216 elems
  const size_t PE = (size_t)BB*NP*NP*HH;       // 33,554,432
  const size_t ME = (size_t)BB*NM*NM*HH;       //  8,388,608
  char* ws = (char*)d_ws;
  size_t off = 0;
  bf16* ab1 = (bf16*)(ws + off); off += ZE * 2;
  bf16* ab2 = (bf16*)(ws + off); off += ZE * 2;
  bf16* eg  = (bf16*)(ws + off); off += ZE * 2;
  bf16* ppg = (bf16*)(ws + off); off += PE * 2;
  bf16* mpg = (bf16*)(ws + off); off += ME * 2;
  float* bsum = (float*)(ws + off); off += ZE * 4;
  if (ws_size < off) return;   // insufficient workspace -> leave output zero (diagnostic)

  // 1) z: LN + gate1 -> ab1, gate2 -> ab2, sigmoid(egw) -> eg   (masked)
  ln_gate_kernel<1><<<(BB*NP*NM)/64, 256, 0, stream>>>(
      z, zmask, ln_g, ln_b,
      gw1, gb1, w1, b1, ab1,
      gw2, gb2, w2, b2, ab2,
      egw, egb, eg);
  // 2) pocket_pair: LN + gate2 -> ppg
  ln_gate_kernel<0><<<(BB*NP*NP)/64, 256, 0, stream>>>(
      pp, nullptr, ln_g, ln_b,
      gw2, gb2, w2, b2, ppg,
      nullptr, nullptr, nullptr, nullptr, nullptr,
      nullptr, nullptr, nullptr);
  // 3) mol_pair: LN + gate1 -> mpg
  ln_gate_kernel<0><<<(BB*NM*NM)/64, 256, 0, stream>>>(
      mp, nullptr, ln_g, ln_b,
      gw1, gb1, w1, b1, mpg,
      nullptr, nullptr, nullptr, nullptr, nullptr,
      nullptr, nullptr, nullptr);
  // 4) both einsums -> bsum
  einsum_kernel<<<dim3(256, BB), 256, 0, stream>>>(ppg, ab1, ab2, mpg, bsum);
  // 5) LN(bsum) + @asw + eg*mask -> out
  final_kernel<<<(BB*NP*NM)/64, 256, 0, stream>>>(
      bsum, eg, zmask, lnh_g, lnh_b, asw, asb, out);
}

// Round 2
// 279.568 us; speedup vs baseline: 8.3756x; 8.3756x over previous
//
#include <hip/hip_runtime.h>
#include <hip/hip_bf16.h>

#define DEVFN __device__ __forceinline__
using bf16 = __hip_bfloat16;
typedef __attribute__((ext_vector_type(8))) short short8;
typedef __attribute__((ext_vector_type(4))) float f32x4;
typedef __attribute__((ext_vector_type(4))) unsigned short us4;

constexpr int BB = 4, NP = 256, NM = 128, CC = 128, HH = 128;
constexpr float EPS = 1e-5f;

#define MFMA16(a,b,c) __builtin_amdgcn_mfma_f32_16x16x32_bf16((a),(b),(c),0,0,0)

DEVFN unsigned short bfbits(float v){ union{ bf16 b; unsigned short s; } u; u.b = __float2bfloat16(v); return u.s; }
DEVFN float bits2f(unsigned short s){ union{ unsigned int i; float f; } u; u.i = ((unsigned)s) << 16; return u.f; }
DEVFN float sigm(float x){ return 1.0f / (1.0f + __expf(-x)); }

// ============================================================================
// prep: convert 6 weight matrices (128x128 f32, [k][n]) -> bf16 transposed
// Wt[n][k]  (B^T layout: B-fragment = contiguous 16B per lane)
// matrix order: 0:gw1 1:w1 2:gw2 3:w2 4:egw 5:asw
// ============================================================================
__global__ __launch_bounds__(256)
void prep_weights_kernel(const float* __restrict__ gw1, const float* __restrict__ w1,
                         const float* __restrict__ gw2, const float* __restrict__ w2,
                         const float* __restrict__ egw, const float* __restrict__ asw,
                         bf16* __restrict__ wt)
{
  __shared__ float wl[128][129];
  const int bx = blockIdx.x;
  const float* W = (bx==0)?gw1 : (bx==1)?w1 : (bx==2)?gw2 : (bx==3)?w2 : (bx==4)?egw : asw;
  const int t = threadIdx.x;
  for (int i = 0; i < 16; ++i){
    int idx = t + 256*i;             // 4096 float4s
    int k = idx >> 5, n0 = (idx & 31) * 4;
    float4 v = *reinterpret_cast<const float4*>(W + k*128 + n0);
    wl[k][n0] = v.x; wl[k][n0+1] = v.y; wl[k][n0+2] = v.z; wl[k][n0+3] = v.w;
  }
  __syncthreads();
  short* o = reinterpret_cast<short*>(wt) + bx * 16384;
  const int n = t >> 1, kh = t & 1;
  #pragma unroll
  for (int j = 0; j < 8; ++j){
    short8 p;
    #pragma unroll
    for (int u = 0; u < 8; ++u) p[u] = (short)bfbits(wl[kh*64 + j*8 + u][n]);
    *reinterpret_cast<short8*>(o + n*128 + kh*64 + j*8) = p;
  }
}

// ============================================================================
// gate kernels: LN(x) then up to: gate-pass (g,l)->o1, gate-pass->o2, eg-pass
// outputs channel-major: out[(b*128+h)*R + rowflat]  (bf16)
// ============================================================================
struct GateSmem {
  short xs[128*128];     // swizzled bf16 A-tile: byte (r*256 + 2c) ^ ((r&7)<<4)
  float lgb[2][128];
  float mu[128], rs[128], mk[128];
};

DEVFN void gate_pass(const char* xb, const float* mk, int t, int b, long rowb, long R,
                     const short* wtg, const short* wtl,
                     const float* __restrict__ bgp, const float* __restrict__ blp,
                     bf16* __restrict__ outp)
{
  const int l = t & 63, w = t >> 6, lr = l & 15, lg = l >> 4;
  const int n0 = w * 32;
  short8 bgf[2][4], blf[2][4];
  #pragma unroll
  for (int nt = 0; nt < 2; ++nt)
    #pragma unroll
    for (int ks = 0; ks < 4; ++ks){
      int n = n0 + nt*16 + lr, ko = ks*32 + lg*8;
      bgf[nt][ks] = *reinterpret_cast<const short8*>(wtg + n*128 + ko);
      blf[nt][ks] = *reinterpret_cast<const short8*>(wtl + n*128 + ko);
    }
  float bgv[2] = { bgp[n0 + lr], bgp[n0 + 16 + lr] };
  float blv[2] = { blp[n0 + lr], blp[n0 + 16 + lr] };
  unsigned short* ob = reinterpret_cast<unsigned short*>(outp);

  for (int mt = 0; mt < 8; ++mt){
    f32x4 zv = {0.f,0.f,0.f,0.f};
    f32x4 ag0 = zv, ag1 = zv, al0 = zv, al1 = zv;
    #pragma unroll
    for (int ks = 0; ks < 4; ++ks){
      int m = mt*16 + lr, ko = ks*32 + lg*8;
      short8 a = *reinterpret_cast<const short8*>(xb + ((m*256 + ko*2) ^ ((m & 7) << 4)));
      ag0 = MFMA16(a, bgf[0][ks], ag0);
      ag1 = MFMA16(a, bgf[1][ks], ag1);
      al0 = MFMA16(a, blf[0][ks], al0);
      al1 = MFMA16(a, blf[1][ks], al1);
    }
    #pragma unroll
    for (int nt = 0; nt < 2; ++nt){
      f32x4 ag = nt ? ag1 : ag0, al = nt ? al1 : al0;
      int h = n0 + nt*16 + lr;
      us4 pk;
      #pragma unroll
      for (int rg = 0; rg < 4; ++rg){
        int rowl = mt*16 + lg*4 + rg;
        float val = sigm(ag[rg] + bgv[nt]) * (al[rg] + blv[nt]) * mk[rowl];
        pk[rg] = bfbits(val);
      }
      *reinterpret_cast<us4*>(ob + (long)(b*128 + h)*R + rowb + mt*16 + lg*4) = pk;
    }
  }
}

DEVFN void eg_pass(const char* xb, int t, int b, long rowb, long R,
                   const short* wtg, const float* __restrict__ bgp, bf16* __restrict__ outp)
{
  const int l = t & 63, w = t >> 6, lr = l & 15, lg = l >> 4;
  const int n0 = w * 32;
  short8 bgf[2][4];
  #pragma unroll
  for (int nt = 0; nt < 2; ++nt)
    #pragma unroll
    for (int ks = 0; ks < 4; ++ks){
      int n = n0 + nt*16 + lr, ko = ks*32 + lg*8;
      bgf[nt][ks] = *reinterpret_cast<const short8*>(wtg + n*128 + ko);
    }
  float bgv[2] = { bgp[n0 + lr], bgp[n0 + 16 + lr] };
  unsigned short* ob = reinterpret_cast<unsigned short*>(outp);

  for (int mt = 0; mt < 8; ++mt){
    f32x4 zv = {0.f,0.f,0.f,0.f};
    f32x4 ag0 = zv, ag1 = zv;
    #pragma unroll
    for (int ks = 0; ks < 4; ++ks){
      int m = mt*16 + lr, ko = ks*32 + lg*8;
      short8 a = *reinterpret_cast<const short8*>(xb + ((m*256 + ko*2) ^ ((m & 7) << 4)));
      ag0 = MFMA16(a, bgf[0][ks], ag0);
      ag1 = MFMA16(a, bgf[1][ks], ag1);
    }
    #pragma unroll
    for (int nt = 0; nt < 2; ++nt){
      f32x4 ag = nt ? ag1 : ag0;
      int h = n0 + nt*16 + lr;
      us4 pk;
      #pragma unroll
      for (int rg = 0; rg < 4; ++rg) pk[rg] = bfbits(sigm(ag[rg] + bgv[nt]));
      *reinterpret_cast<us4*>(ob + (long)(b*128 + h)*R + rowb + mt*16 + lg*4) = pk;
    }
  }
}

template<int NPASS>
__global__ __launch_bounds__(256, 3)
void gate_mfma_kernel(const float* __restrict__ x, const float* __restrict__ mask,
                      const float* __restrict__ lng, const float* __restrict__ lnb,
                      const bf16* __restrict__ wt,
                      int m1g, int m1l, const float* __restrict__ bg1p, const float* __restrict__ bl1p, bf16* __restrict__ o1,
                      int m2g, int m2l, const float* __restrict__ bg2p, const float* __restrict__ bl2p, bf16* __restrict__ o2,
                      const float* __restrict__ bgep, bf16* __restrict__ oe,
                      long R)
{
  __shared__ GateSmem sm;
  const int t = threadIdx.x;
  const long row0 = (long)blockIdx.x * 128;
  const int b = (int)(row0 / R);
  const long rowb = row0 - (long)b * R;

  if (t < 128){
    sm.lgb[0][t] = lng[t];
    sm.lgb[1][t] = lnb[t];
    sm.mk[t] = mask ? mask[row0 + t] : 1.0f;
  }
  // ---- LN: 2 threads per row, data kept in registers ----
  const int r = t >> 1, hf = t & 1;
  const float4* xrow = reinterpret_cast<const float4*>(x + (row0 + r)*128 + hf*64);
  float4 vb[16];
  float s = 0.f, ss = 0.f;
  #pragma unroll
  for (int i = 0; i < 16; ++i){
    float4 v = xrow[i]; vb[i] = v;
    s  += v.x + v.y + v.z + v.w;
    ss += v.x*v.x + v.y*v.y + v.z*v.z + v.w*v.w;
  }
  s  += __shfl_xor(s, 1);
  ss += __shfl_xor(ss, 1);
  if (!hf){
    float mu = s * (1.f/128.f);
    float var = ss * (1.f/128.f) - mu*mu;
    sm.mu[r] = mu;
    sm.rs[r] = rsqrtf(var + EPS);
  }
  __syncthreads();
  {
    const float mu = sm.mu[r], rg = sm.rs[r];
    char* xb = reinterpret_cast<char*>(sm.xs);
    #pragma unroll
    for (int j = 0; j < 8; ++j){
      float4 a = vb[2*j], c2 = vb[2*j+1];
      float vv[8] = {a.x, a.y, a.z, a.w, c2.x, c2.y, c2.z, c2.w};
      short8 p;
      #pragma unroll
      for (int u = 0; u < 8; ++u){
        int ch = hf*64 + j*8 + u;
        p[u] = (short)bfbits((vv[u] - mu) * rg * sm.lgb[0][ch] + sm.lgb[1][ch]);
      }
      *reinterpret_cast<short8*>(xb + ((r*256 + hf*128 + j*16) ^ ((r & 7) << 4))) = p;
    }
  }
  __syncthreads();

  const char* xb = reinterpret_cast<const char*>(sm.xs);
  const short* wts = reinterpret_cast<const short*>(wt);
  gate_pass(xb, sm.mk, t, b, rowb, R, wts + m1g*16384, wts + m1l*16384, bg1p, bl1p, o1);
  if (NPASS == 3){
    gate_pass(xb, sm.mk, t, b, rowb, R, wts + m2g*16384, wts + m2l*16384, bg2p, bl2p, o2);
    eg_pass(xb, t, b, rowb, R, wts + 4*16384, bgep, oe);
  }
}

// ============================================================================
// einsum: per (b,c) block: bsum[b,c,i,j] = sum_k ppg[b,c,i,k]*ab1[b,c,k,j]
//                                        + sum_k ab2[b,c,i,k]*mpg[b,c,j,k]
// ab1 staged once to LDS transposed [j][k] (XOR swizzled).
// ============================================================================
__global__ __launch_bounds__(256, 2)
void einsum_mfma_kernel(const bf16* __restrict__ ppg, const bf16* __restrict__ ab1,
                        const bf16* __restrict__ ab2, const bf16* __restrict__ mpg,
                        float* __restrict__ bsum)
{
  __shared__ short b1t[128*256];   // [j=128][k=256] bf16, byte (j*512+2k)^((j&7)<<4)
  const int t = threadIdx.x, l = t & 63, w = t >> 6, lr = l & 15, lg = l >> 4;
  const int bc = blockIdx.x;
  const short* A1 = reinterpret_cast<const short*>(ppg) + (long)bc * (NP*NP);
  const short* B1 = reinterpret_cast<const short*>(ab1) + (long)bc * (NP*NM);
  const short* A2 = reinterpret_cast<const short*>(ab2) + (long)bc * (NP*NM);
  const short* B2 = reinterpret_cast<const short*>(mpg) + (long)bc * (NM*NM);

  // stage + transpose ab1 (256k x 128j -> LDS [j][k])
  char* lb = reinterpret_cast<char*>(b1t);
  for (int it = 0; it < 16; ++it){
    int idx = t + 256*it;               // 4096 chunks of 8 bf16
    int k = idx >> 4, j0 = (idx & 15) * 8;
    short8 v = *reinterpret_cast<const short8*>(B1 + idx*8);
    #pragma unroll
    for (int u = 0; u < 8; ++u){
      int j = j0 + u;
      *reinterpret_cast<short*>(lb + ((j*512 + k*2) ^ ((j & 7) << 4))) = v[u];
    }
  }
  __syncthreads();

  f32x4 zv = {0.f,0.f,0.f,0.f};
  f32x4 acc[4][8];
  #pragma unroll
  for (int i = 0; i < 4; ++i)
    #pragma unroll
    for (int j = 0; j < 8; ++j) acc[i][j] = zv;

  const int m0 = w * 64;
  // ---- e1: K = 256 ----
  for (int ks = 0; ks < 8; ++ks){
    int ko = ks*32 + lg*8;
    short8 af[4];
    #pragma unroll
    for (int mt = 0; mt < 4; ++mt)
      af[mt] = *reinterpret_cast<const short8*>(A1 + (m0 + mt*16 + lr)*256 + ko);
    short8 bf[8];
    #pragma unroll
    for (int nt = 0; nt < 8; ++nt){
      int n = nt*16 + lr;
      bf[nt] = *reinterpret_cast<const short8*>(lb + ((n*512 + ko*2) ^ ((n & 7) << 4)));
    }
    #pragma unroll
    for (int mt = 0; mt < 4; ++mt)
      #pragma unroll
      for (int nt = 0; nt < 8; ++nt)
        acc[mt][nt] = MFMA16(af[mt], bf[nt], acc[mt][nt]);
  }
  // ---- e2: K = 128 ----
  for (int ks = 0; ks < 4; ++ks){
    int ko = ks*32 + lg*8;
    short8 af[4];
    #pragma unroll
    for (int mt = 0; mt < 4; ++mt)
      af[mt] = *reinterpret_cast<const short8*>(A2 + (m0 + mt*16 + lr)*128 + ko);
    short8 bf[8];
    #pragma unroll
    for (int nt = 0; nt < 8; ++nt)
      bf[nt] = *reinterpret_cast<const short8*>(B2 + (nt*16 + lr)*128 + ko);
    #pragma unroll
    for (int mt = 0; mt < 4; ++mt)
      #pragma unroll
      for (int nt = 0; nt < 8; ++nt)
        acc[mt][nt] = MFMA16(af[mt], bf[nt], acc[mt][nt]);
  }
  // store f32 [i][j]
  float* out = bsum + (long)bc * (NP*NM);
  #pragma unroll
  for (int mt = 0; mt < 4; ++mt)
    #pragma unroll
    for (int nt = 0; nt < 8; ++nt)
      #pragma unroll
      for (int rg = 0; rg < 4; ++rg)
        out[(m0 + mt*16 + lg*4 + rg)*128 + nt*16 + lr] = acc[mt][nt][rg];
}

// ============================================================================
// final: h = LN_c(bsum[b,c,ij]); out[ij,co] = eg[b,co,ij]*(h@asw + asb)*mask
// ============================================================================
__global__ __launch_bounds__(256, 2)
void final_mfma_kernel(const float* __restrict__ bsum, const bf16* __restrict__ eg,
                       const float* __restrict__ mask,
                       const float* __restrict__ lnhg, const float* __restrict__ lnhb,
                       const bf16* __restrict__ wt, const float* __restrict__ asb,
                       float* __restrict__ out)
{
  __shared__ struct {
    float xsT[128][68];     // [c][ij] f32
    short xs[64*128];       // swizzled bf16 A-tile [ij][c]
    float lgb[2][128];
    float ps[4][64], pss[4][64];
    float mu[64], rs[64], mk[64];
  } sm;
  const int t = threadIdx.x, l = t & 63, w = t >> 6, lr = l & 15, lg = l >> 4;
  const long row0 = (long)blockIdx.x * 64;
  const int b = (int)(row0 >> 15);          // 32768 rows per batch
  const long rowb = row0 & 32767;

  if (t < 128){ sm.lgb[0][t] = lnhg[t]; sm.lgb[1][t] = lnhb[t]; }
  if (t < 64) sm.mk[t] = mask[row0 + t];

  // stage bsum tile -> xsT[c][ij]
  for (int i = 0; i < 8; ++i){
    int idx = t + 256*i;              // 2048 float4s: 128c x 16
    int c = idx >> 4, j4 = idx & 15;
    float4 v = *reinterpret_cast<const float4*>(bsum + (long)(b*128 + c)*32768 + rowb + j4*4);
    *reinterpret_cast<float4*>(&sm.xsT[c][j4*4]) = v;
  }
  __syncthreads();
  {
    int ij = t & 63, q = t >> 6;
    float s = 0.f, ss = 0.f;
    #pragma unroll
    for (int k = 0; k < 32; ++k){
      float v = sm.xsT[q*32 + k][ij];
      s += v; ss += v*v;
    }
    sm.ps[q][ij] = s; sm.pss[q][ij] = ss;
  }
  __syncthreads();
  if (t < 64){
    float s  = sm.ps[0][t] + sm.ps[1][t] + sm.ps[2][t] + sm.ps[3][t];
    float ss = sm.pss[0][t] + sm.pss[1][t] + sm.pss[2][t] + sm.pss[3][t];
    float mu = s * (1.f/128.f);
    float var = ss * (1.f/128.f) - mu*mu;
    sm.mu[t] = mu; sm.rs[t] = rsqrtf(var + EPS);
  }
  __syncthreads();
  {
    int ij = t & 63, q = t >> 6;
    float mu = sm.mu[ij], rg = sm.rs[ij];
    char* xb = reinterpret_cast<char*>(sm.xs);
    #pragma unroll
    for (int u = 0; u < 4; ++u){
      short8 p;
      #pragma unroll
      for (int e = 0; e < 8; ++e){
        int c = q*32 + u*8 + e;
        p[e] = (short)bfbits((sm.xsT[c][ij] - mu) * rg * sm.lgb[0][c] + sm.lgb[1][c]);
      }
      *reinterpret_cast<short8*>(xb + ((ij*256 + q*64 + u*16) ^ ((ij & 7) << 4))) = p;
    }
  }
  __syncthreads();

  // MFMA: wave w owns rows w*16..w*16+15, full N=128
  const short* aswt = reinterpret_cast<const short*>(wt) + 5*16384;
  short8 bfr[8][4];
  #pragma unroll
  for (int nt = 0; nt < 8; ++nt)
    #pragma unroll
    for (int ks = 0; ks < 4; ++ks)
      bfr[nt][ks] = *reinterpret_cast<const short8*>(aswt + (nt*16 + lr)*128 + ks*32 + lg*8);

  f32x4 zv = {0.f,0.f,0.f,0.f};
  f32x4 acc[8];
  #pragma unroll
  for (int i = 0; i < 8; ++i) acc[i] = zv;
  const char* xb = reinterpret_cast<const char*>(sm.xs);
  #pragma unroll
  for (int ks = 0; ks < 4; ++ks){
    int m = w*16 + lr, ko = ks*32 + lg*8;
    short8 a = *reinterpret_cast<const short8*>(xb + ((m*256 + ko*2) ^ ((m & 7) << 4)));
    #pragma unroll
    for (int nt = 0; nt < 8; ++nt)
      acc[nt] = MFMA16(a, bfr[nt][ks], acc[nt]);
  }
  // epilogue
  const unsigned short* egb = reinterpret_cast<const unsigned short*>(eg);
  #pragma unroll
  for (int nt = 0; nt < 8; ++nt){
    int co = nt*16 + lr;
    float bias = asb[co];
    us4 egv = *reinterpret_cast<const us4*>(egb + (long)(b*128 + co)*32768 + rowb + w*16 + lg*4);
    #pragma unroll
    for (int rg = 0; rg < 4; ++rg){
      int rowl = w*16 + lg*4 + rg;
      float val = bits2f(egv[rg]) * (acc[nt][rg] + bias) * sm.mk[rowl];
      out[(row0 + rowl)*128 + co] = val;
    }
  }
}

// ============================================================================
extern "C" void kernel_launch(void* const* d_in, const int* in_sizes, int n_in,
                              void* d_out, int out_size, void* d_ws, size_t ws_size,
                              hipStream_t stream)
{
  const float* z     = (const float*)d_in[0];
  const float* zmask = (const float*)d_in[1];
  const float* pp    = (const float*)d_in[2];
  const float* mp    = (const float*)d_in[3];
  const float* ln_g  = (const float*)d_in[4];
  const float* ln_b  = (const float*)d_in[5];
  const float* lnh_g = (const float*)d_in[6];
  const float* lnh_b = (const float*)d_in[7];
  const float* gw1   = (const float*)d_in[8];
  const float* gb1   = (const float*)d_in[9];
  const float* gw2   = (const float*)d_in[10];
  const float* gb2   = (const float*)d_in[11];
  const float* w1    = (const float*)d_in[12];
  const float* b1    = (const float*)d_in[13];
  const float* w2    = (const float*)d_in[14];
  const float* b2    = (const float*)d_in[15];
  const float* egw   = (const float*)d_in[16];
  const float* egb   = (const float*)d_in[17];
  const float* asw   = (const float*)d_in[18];
  const float* asb   = (const float*)d_in[19];
  float* out = (float*)d_out;

  const size_t ZE = (size_t)BB*NP*NM*HH;   // 16,777,216
  const size_t PE = (size_t)BB*NP*NP*HH;   // 33,554,432
  const size_t ME = (size_t)BB*NM*NM*HH;   //  8,388,608
  char* ws = (char*)d_ws;
  size_t off = 0;
  bf16* wt   = (bf16*)(ws + off); off += 6 * 16384 * 2;   // 196,608
  bf16* ab1  = (bf16*)(ws + off); off += ZE * 2;
  bf16* ab2  = (bf16*)(ws + off); off += ZE * 2;
  bf16* egp  = (bf16*)(ws + off); off += ZE * 2;
  bf16* ppg  = (bf16*)(ws + off); off += PE * 2;
  bf16* mpg  = (bf16*)(ws + off); off += ME * 2;
  float* bsum = (float*)(ws + off); off += ZE * 4;
  if (ws_size < off) return;

  prep_weights_kernel<<<6, 256, 0, stream>>>(gw1, w1, gw2, w2, egw, asw, wt);

  // z: LN + gate1->ab1, gate2->ab2, eg (masked), R = 32768
  gate_mfma_kernel<3><<<(BB*NP*NM)/128, 256, 0, stream>>>(
      z, zmask, ln_g, ln_b, wt,
      0, 1, gb1, b1, ab1,
      2, 3, gb2, b2, ab2,
      egb, egp, (long)(NP*NM));
  // pp: LN + gate2 -> ppg, R = 65536
  gate_mfma_kernel<1><<<(BB*NP*NP)/128, 256, 0, stream>>>(
      pp, nullptr, ln_g, ln_b, wt,
      2, 3, gb2, b2, ppg,
      0, 0, nullptr, nullptr, nullptr,
      nullptr, nullptr, (long)(NP*NP));
  // mp: LN + gate1 -> mpg, R = 16384
  gate_mfma_kernel<1><<<(BB*NM*NM)/128, 256, 0, stream>>>(
      mp, nullptr, ln_g, ln_b, wt,
      0, 1, gb1, b1, mpg,
      0, 0, nullptr, nullptr, nullptr,
      nullptr, nullptr, (long)(NM*NM));

  einsum_mfma_kernel<<<BB*CC, 256, 0, stream>>>(ppg, ab1, ab2, mpg, bsum);

  final_mfma_kernel<<<(BB*NP*NM)/64, 256, 0, stream>>>(
      bsum, egp, zmask, lnh_g, lnh_b, wt, asb, out);
}